// Round 4
// baseline (83.734 us; speedup 1.0000x reference)
//
#include <hip/hip_runtime.h>
#include <math.h>

#define BATCH 128
#define HH 256
#define WW 256
#define HW (HH * WW)
#define HW4 (HW / 4)
#define CHUNKS (HW4 / 256)  // 64 blocks per batch
#define NKPT 68

typedef float fx4 __attribute__((ext_vector_type(4)));

__device__ inline double wave_sum64(double v) {
#pragma unroll
    for (int off = 32; off > 0; off >>= 1) v += __shfl_xor(v, off);
    return v;
}

// ---------------------------------------------------------------------------
// Fused kernel. One block = 256 threads handles 1024 contiguous pixels of one
// batch. Each block redundantly computes its batch's similarity transform on
// wave 0 (gather 68 kpts -> butterfly reductions -> serial 3x3 Jacobi on lane
// 0 in double), broadcast via 12 LDS floats. The block's streaming Offset
// loads are issued BEFORE the tform phase so HBM latency hides under it.
// ---------------------------------------------------------------------------
__global__ __launch_bounds__(256, 4) void fused_kernel(
    const float* __restrict__ Offset, const float* __restrict__ Posmap,
    const float* __restrict__ meanp, const int* __restrict__ uv,
    float* __restrict__ Out) {
    __shared__ float rt_s[12];

    const int b = blockIdx.x / CHUNKS;
    const int p = (blockIdx.x % CHUNKS) * 256 + threadIdx.x;
    const size_t base4 = (size_t)b * 3 * HW4;

    // --- issue streaming loads early (latency hides under tform) ---
    const fx4* Off4 = (const fx4*)Offset;
    fx4 o0 = Off4[base4 + p];
    fx4 o1 = Off4[base4 + HW4 + p];
    fx4 o2 = Off4[base4 + 2 * HW4 + p];

    // --- per-batch transform on wave 0 ---
    if (threadIdx.x < 64) {
        const int lane = threadIdx.x;
        const float* offb = Offset + (size_t)b * 3 * HW;
        const float* dstb = Posmap + (size_t)b * 3 * HW;
        const bool has1 = lane < (NKPT - 64);  // lanes 0..3 carry kpt lane+64

        double s0[3], d0[3], s1[3] = {0, 0, 0}, d1[3] = {0, 0, 0};
        {
            const int p0 = uv[lane * 2 + 0] * WW + uv[lane * 2 + 1];
#pragma unroll
            for (int i = 0; i < 3; i++) {
                s0[i] = (double)offb[(size_t)i * HW + p0] * 6.0 +
                        (double)meanp[(size_t)i * HW + p0];
                d0[i] = (double)dstb[(size_t)i * HW + p0];
            }
            if (has1) {
                const int k1 = lane + 64;
                const int p1 = uv[k1 * 2 + 0] * WW + uv[k1 * 2 + 1];
#pragma unroll
                for (int i = 0; i < 3; i++) {
                    s1[i] = (double)offb[(size_t)i * HW + p1] * 6.0 +
                            (double)meanp[(size_t)i * HW + p1];
                    d1[i] = (double)dstb[(size_t)i * HW + p1];
                }
            }
        }

        double s33[3], d33[3];
#pragma unroll
        for (int i = 0; i < 3; i++) {
            s33[i] = __shfl(s0[i], 33);
            d33[i] = __shfl(d0[i], 33);
        }

        double ns0 = 0, nd0 = 0, ns1 = 0, nd1 = 0;
        double ssum[3], dsum[3];
#pragma unroll
        for (int i = 0; i < 3; i++) {
            double es = s0[i] - s33[i], ed = d0[i] - d33[i];
            ns0 += es * es;
            nd0 += ed * ed;
            es = s1[i] - s33[i];
            ed = d1[i] - d33[i];
            ns1 += es * es;
            nd1 += ed * ed;
            ssum[i] = s0[i] + s1[i];
            dsum[i] = d0[i] + d1[i];
        }
        double sd1p = sqrt(ns0) + (has1 ? sqrt(ns1) : 0.0);
        double sd2p = sqrt(nd0) + (has1 ? sqrt(nd1) : 0.0);

        const double sd1 = wave_sum64(sd1p);
        const double sd2 = wave_sum64(sd2p);
#pragma unroll
        for (int i = 0; i < 3; i++) {
            ssum[i] = wave_sum64(ssum[i]);
            dsum[i] = wave_sum64(dsum[i]);
        }

        const double s = sd2 / sd1;
        double sbar[3], dbar[3];
#pragma unroll
        for (int i = 0; i < 3; i++) {
            sbar[i] = ssum[i] / NKPT;
            dbar[i] = dsum[i] / NKPT;
        }

        double Hm[3][3];
        {
            double aa0[3], bb0[3], aa1[3], bb1[3];
#pragma unroll
            for (int i = 0; i < 3; i++) {
                aa0[i] = (s0[i] - sbar[i]) * s;
                bb0[i] = d0[i] - dbar[i];
                aa1[i] = has1 ? (s1[i] - sbar[i]) * s : 0.0;
                bb1[i] = has1 ? (d1[i] - dbar[i]) : 0.0;
            }
#pragma unroll
            for (int i = 0; i < 3; i++)
#pragma unroll
                for (int j = 0; j < 3; j++)
                    Hm[i][j] = wave_sum64(aa0[i] * bb0[j] + aa1[i] * bb1[j]);
        }

        if (lane == 0) {
            // G = Hm^T Hm
            double A[3][3];
            for (int i = 0; i < 3; i++)
                for (int j = 0; j < 3; j++) {
                    double acc = 0;
                    for (int kk = 0; kk < 3; kk++) acc += Hm[kk][i] * Hm[kk][j];
                    A[i][j] = acc;
                }

            double V[3][3] = {{1, 0, 0}, {0, 1, 0}, {0, 0, 1}};
            for (int sweep = 0; sweep < 12; ++sweep) {
                double off = fabs(A[0][1]) + fabs(A[0][2]) + fabs(A[1][2]);
                double diag = fabs(A[0][0]) + fabs(A[1][1]) + fabs(A[2][2]);
                if (off <= diag * 1e-15) break;
                for (int pp = 0; pp < 2; pp++)
                    for (int q = pp + 1; q < 3; q++) {
                        double apq = A[pp][q];
                        if (fabs(apq) < 1e-300) continue;
                        double theta = (A[q][q] - A[pp][pp]) / (2.0 * apq);
                        double t = (theta >= 0.0 ? 1.0 : -1.0) /
                                   (fabs(theta) + sqrt(theta * theta + 1.0));
                        double c = 1.0 / sqrt(t * t + 1.0);
                        double sn = t * c;
                        A[pp][pp] -= t * apq;
                        A[q][q] += t * apq;
                        A[pp][q] = 0.0;
                        A[q][pp] = 0.0;
                        int r = 3 - pp - q;
                        double arp = A[r][pp], arq = A[r][q];
                        A[r][pp] = A[pp][r] = c * arp - sn * arq;
                        A[r][q] = A[q][r] = sn * arp + c * arq;
#pragma unroll
                        for (int rr = 0; rr < 3; rr++) {
                            double vrp = V[rr][pp], vrq = V[rr][q];
                            V[rr][pp] = c * vrp - sn * vrq;
                            V[rr][q] = sn * vrp + c * vrq;
                        }
                    }
            }
            double isig[3];
#pragma unroll
            for (int i = 0; i < 3; i++) {
                double l = A[i][i];
                if (l < 1e-30) l = 1e-30;
                isig[i] = 1.0 / sqrt(l);
            }
            double Wm[3][3];
            for (int i = 0; i < 3; i++)
                for (int j = 0; j < 3; j++) {
                    double acc = 0;
                    for (int kk = 0; kk < 3; kk++)
                        acc += V[i][kk] * V[j][kk] * isig[kk];
                    Wm[i][j] = acc;
                }
            double R[3][3];
            for (int i = 0; i < 3; i++)
                for (int j = 0; j < 3; j++) {
                    double acc = 0;
                    for (int kk = 0; kk < 3; kk++) acc += Wm[i][kk] * Hm[j][kk];
                    R[i][j] = acc;
                }
            for (int j = 0; j < 3; j++) {
                for (int i = 0; i < 3; i++)
                    rt_s[j * 3 + i] = (float)(R[j][i] * s);
                double tj = dbar[j];
                for (int i = 0; i < 3; i++) tj -= s * sbar[i] * R[j][i];
                rt_s[9 + j] = (float)tj;
            }
        }
    }
    __syncthreads();

    const float r00 = rt_s[0], r01 = rt_s[1], r02 = rt_s[2];
    const float r10 = rt_s[3], r11 = rt_s[4], r12 = rt_s[5];
    const float r20 = rt_s[6], r21 = rt_s[7], r22 = rt_s[8];
    const float t0 = rt_s[9], t1 = rt_s[10], t2 = rt_s[11];

    const fx4* Mean4 = (const fx4*)meanp;
    fx4 m0 = Mean4[p];
    fx4 m1 = Mean4[HW4 + p];
    fx4 m2 = Mean4[2 * HW4 + p];

    fx4 y0, y1, y2;
#pragma unroll
    for (int c = 0; c < 4; c++) {
        float x0 = fmaf(o0[c], 6.0f, m0[c]);
        float x1 = fmaf(o1[c], 6.0f, m1[c]);
        float x2 = fmaf(o2[c], 6.0f, m2[c]);
        y0[c] = fmaf(x0, r00, fmaf(x1, r01, fmaf(x2, r02, t0)));
        y1[c] = fmaf(x0, r10, fmaf(x1, r11, fmaf(x2, r12, t1)));
        y2[c] = fmaf(x0, r20, fmaf(x1, r21, fmaf(x2, r22, t2)));
    }

    fx4* Out4 = (fx4*)Out;
    __builtin_nontemporal_store(y0, &Out4[base4 + p]);
    __builtin_nontemporal_store(y1, &Out4[base4 + HW4 + p]);
    __builtin_nontemporal_store(y2, &Out4[base4 + 2 * HW4 + p]);
}

extern "C" void kernel_launch(void* const* d_in, const int* in_sizes, int n_in,
                              void* d_out, int out_size, void* d_ws,
                              size_t ws_size, hipStream_t stream) {
    const float* Offset = (const float*)d_in[0];
    const float* Posmap = (const float*)d_in[1];
    const float* meanp = (const float*)d_in[2];
    const int* uv = (const int*)d_in[3];
    float* out = (float*)d_out;

    fused_kernel<<<BATCH * CHUNKS, 256, 0, stream>>>(Offset, Posmap, meanp, uv,
                                                     out);
}

// Round 5
// 43.670 us; speedup vs baseline: 1.9174x; 1.9174x over previous
//
#include <hip/hip_runtime.h>
#include <math.h>

#define BATCH 128
#define HH 256
#define WW 256
#define HW (HH * WW)
#define HW4 (HW / 4)
#define NKPT 68

typedef float fx4 __attribute__((ext_vector_type(4)));

__device__ inline double wave_sum64(double v) {
#pragma unroll
    for (int off = 32; off > 0; off >>= 1) v += __shfl_xor(v, off);
    return v;
}

// ---------------------------------------------------------------------------
// Kernel A: per-batch similarity transform. One wave per batch, 128 blocks.
// Single butterfly-reduction phase: sd1, sd2, ssum[3], dsum[3] and the raw
// product matrix P[3][3] are all independent (the scale s is NOT needed
// before the covariance because the polar factor is scale-invariant:
// polar(c*H) = polar(H) for c > 0). H = P - N*sbar*dbar^T is formed on lane
// 0, followed by the 3x3 Jacobi polar decomposition in double.
// Writes 12 floats per batch into RT: Rs[3][3] row-major (already *s), t[3].
// ---------------------------------------------------------------------------
__global__ __launch_bounds__(64, 1) void tform_kernel(
    const float* __restrict__ Offset, const float* __restrict__ Posmap,
    const float* __restrict__ meanp, const int* __restrict__ uv,
    float* __restrict__ RT) {
    const int b = blockIdx.x;
    const int lane = threadIdx.x;
    const float* offb = Offset + (size_t)b * 3 * HW;
    const float* dstb = Posmap + (size_t)b * 3 * HW;
    const bool has1 = lane < (NKPT - 64);  // lanes 0..3 carry kpt lane+64

    // Gather keypoint(s) into registers (double).
    double s0[3], d0[3], s1[3] = {0, 0, 0}, d1[3] = {0, 0, 0};
    {
        const int p0 = uv[lane * 2 + 0] * WW + uv[lane * 2 + 1];
#pragma unroll
        for (int i = 0; i < 3; i++) {
            s0[i] = (double)offb[(size_t)i * HW + p0] * 6.0 +
                    (double)meanp[(size_t)i * HW + p0];
            d0[i] = (double)dstb[(size_t)i * HW + p0];
        }
        if (has1) {
            const int k1 = lane + 64;
            const int p1 = uv[k1 * 2 + 0] * WW + uv[k1 * 2 + 1];
#pragma unroll
            for (int i = 0; i < 3; i++) {
                s1[i] = (double)offb[(size_t)i * HW + p1] * 6.0 +
                        (double)meanp[(size_t)i * HW + p1];
                d1[i] = (double)dstb[(size_t)i * HW + p1];
            }
        }
    }

    // Broadcast keypoint 33 (owned by lane 33).
    double s33[3], d33[3];
#pragma unroll
    for (int i = 0; i < 3; i++) {
        s33[i] = __shfl(s0[i], 33);
        d33[i] = __shfl(d0[i], 33);
    }

    // Per-lane partials — ALL independent, one reduction phase.
    double ns0 = 0, nd0 = 0, ns1 = 0, nd1 = 0;
    double ssum[3], dsum[3], P[3][3];
#pragma unroll
    for (int i = 0; i < 3; i++) {
        double es = s0[i] - s33[i], ed = d0[i] - d33[i];
        ns0 += es * es;
        nd0 += ed * ed;
        es = s1[i] - s33[i];
        ed = d1[i] - d33[i];
        ns1 += es * es;
        nd1 += ed * ed;
        ssum[i] = s0[i] + s1[i];
        dsum[i] = d0[i] + d1[i];
#pragma unroll
        for (int j = 0; j < 3; j++) P[i][j] = s0[i] * d0[j] + s1[i] * d1[j];
    }
    double sd1p = sqrt(ns0) + (has1 ? sqrt(ns1) : 0.0);
    double sd2p = sqrt(nd0) + (has1 ? sqrt(nd1) : 0.0);

    const double sd1 = wave_sum64(sd1p);
    const double sd2 = wave_sum64(sd2p);
#pragma unroll
    for (int i = 0; i < 3; i++) {
        ssum[i] = wave_sum64(ssum[i]);
        dsum[i] = wave_sum64(dsum[i]);
    }
#pragma unroll
    for (int i = 0; i < 3; i++)
#pragma unroll
        for (int j = 0; j < 3; j++) P[i][j] = wave_sum64(P[i][j]);

    if (lane != 0) return;

    const double s = sd2 / sd1;
    double sbar[3], dbar[3];
#pragma unroll
    for (int i = 0; i < 3; i++) {
        sbar[i] = ssum[i] / NKPT;
        dbar[i] = dsum[i] / NKPT;
    }

    // Centered covariance (un-scaled): Hm[i][j] = P[i][j] - N*sbar_i*dbar_j
    double Hm[3][3];
    for (int i = 0; i < 3; i++)
        for (int j = 0; j < 3; j++)
            Hm[i][j] = P[i][j] - (double)NKPT * sbar[i] * dbar[j];

    // G = Hm^T Hm (symmetric 3x3)
    double A[3][3];
    for (int i = 0; i < 3; i++)
        for (int j = 0; j < 3; j++) {
            double acc = 0;
            for (int kk = 0; kk < 3; kk++) acc += Hm[kk][i] * Hm[kk][j];
            A[i][j] = acc;
        }

    // Cyclic Jacobi eigendecomposition.
    double V[3][3] = {{1, 0, 0}, {0, 1, 0}, {0, 0, 1}};
    for (int sweep = 0; sweep < 12; ++sweep) {
        double off = fabs(A[0][1]) + fabs(A[0][2]) + fabs(A[1][2]);
        double diag = fabs(A[0][0]) + fabs(A[1][1]) + fabs(A[2][2]);
        if (off <= diag * 1e-15) break;
        for (int pp = 0; pp < 2; pp++)
            for (int q = pp + 1; q < 3; q++) {
                double apq = A[pp][q];
                if (fabs(apq) < 1e-300) continue;
                double theta = (A[q][q] - A[pp][pp]) / (2.0 * apq);
                double t = (theta >= 0.0 ? 1.0 : -1.0) /
                           (fabs(theta) + sqrt(theta * theta + 1.0));
                double c = 1.0 / sqrt(t * t + 1.0);
                double sn = t * c;
                A[pp][pp] -= t * apq;
                A[q][q] += t * apq;
                A[pp][q] = 0.0;
                A[q][pp] = 0.0;
                int r = 3 - pp - q;
                double arp = A[r][pp], arq = A[r][q];
                A[r][pp] = A[pp][r] = c * arp - sn * arq;
                A[r][q] = A[q][r] = sn * arp + c * arq;
#pragma unroll
                for (int rr = 0; rr < 3; rr++) {
                    double vrp = V[rr][pp], vrq = V[rr][q];
                    V[rr][pp] = c * vrp - sn * vrq;
                    V[rr][q] = sn * vrp + c * vrq;
                }
            }
    }
    double isig[3];
#pragma unroll
    for (int i = 0; i < 3; i++) {
        double l = A[i][i];
        if (l < 1e-30) l = 1e-30;
        isig[i] = 1.0 / sqrt(l);
    }
    // Wm = V diag(1/sigma) V^T ;  R = Wm * Hm^T  ( = V U^T of the SVD )
    double Wm[3][3];
    for (int i = 0; i < 3; i++)
        for (int j = 0; j < 3; j++) {
            double acc = 0;
            for (int kk = 0; kk < 3; kk++) acc += V[i][kk] * V[j][kk] * isig[kk];
            Wm[i][j] = acc;
        }
    double R[3][3];
    for (int i = 0; i < 3; i++)
        for (int j = 0; j < 3; j++) {
            double acc = 0;
            for (int kk = 0; kk < 3; kk++) acc += Wm[i][kk] * Hm[j][kk];
            R[i][j] = acc;
        }

    float* rt = RT + b * 12;
    for (int j = 0; j < 3; j++) {
        for (int i = 0; i < 3; i++) rt[j * 3 + i] = (float)(R[j][i] * s);
        double tj = dbar[j];
        for (int i = 0; i < 3; i++) tj -= s * sbar[i] * R[j][i];
        rt[9 + j] = (float)tj;
    }
}

// ---------------------------------------------------------------------------
// Kernel B: out[b,j,h,w] = sum_i (Offset[b,i,h,w]*6 + mean[i,h,w]) * Rs[j][i]
//                          + t[j]
// float4 vectorized, planar, coalesced; nontemporal stores keep the output
// stream from evicting Offset/mean from L3.
// ---------------------------------------------------------------------------
__global__ __launch_bounds__(256) void apply_kernel(
    const fx4* __restrict__ Off, const fx4* __restrict__ Mean,
    const float* __restrict__ RT, fx4* __restrict__ Out) {
    const int CHUNKS = HW4 / 256;  // 64
    const int b = blockIdx.x / CHUNKS;
    const int p = (blockIdx.x % CHUNKS) * 256 + threadIdx.x;

    const size_t base = (size_t)b * 3 * HW4;
    fx4 o0 = Off[base + p];
    fx4 o1 = Off[base + HW4 + p];
    fx4 o2 = Off[base + 2 * HW4 + p];
    fx4 m0 = Mean[p];
    fx4 m1 = Mean[HW4 + p];
    fx4 m2 = Mean[2 * HW4 + p];

    const float* rt = RT + b * 12;
    const float r00 = rt[0], r01 = rt[1], r02 = rt[2];
    const float r10 = rt[3], r11 = rt[4], r12 = rt[5];
    const float r20 = rt[6], r21 = rt[7], r22 = rt[8];
    const float t0 = rt[9], t1 = rt[10], t2 = rt[11];

    fx4 y0, y1, y2;
#pragma unroll
    for (int c = 0; c < 4; c++) {
        float x0 = fmaf(o0[c], 6.0f, m0[c]);
        float x1 = fmaf(o1[c], 6.0f, m1[c]);
        float x2 = fmaf(o2[c], 6.0f, m2[c]);
        y0[c] = fmaf(x0, r00, fmaf(x1, r01, fmaf(x2, r02, t0)));
        y1[c] = fmaf(x0, r10, fmaf(x1, r11, fmaf(x2, r12, t1)));
        y2[c] = fmaf(x0, r20, fmaf(x1, r21, fmaf(x2, r22, t2)));
    }

    __builtin_nontemporal_store(y0, &Out[base + p]);
    __builtin_nontemporal_store(y1, &Out[base + HW4 + p]);
    __builtin_nontemporal_store(y2, &Out[base + 2 * HW4 + p]);
}

extern "C" void kernel_launch(void* const* d_in, const int* in_sizes, int n_in,
                              void* d_out, int out_size, void* d_ws,
                              size_t ws_size, hipStream_t stream) {
    const float* Offset = (const float*)d_in[0];
    const float* Posmap = (const float*)d_in[1];
    const float* meanp = (const float*)d_in[2];
    const int* uv = (const int*)d_in[3];
    float* out = (float*)d_out;
    float* RT = (float*)d_ws;  // 128 * 12 floats

    tform_kernel<<<BATCH, 64, 0, stream>>>(Offset, Posmap, meanp, uv, RT);
    apply_kernel<<<BATCH * (HW4 / 256), 256, 0, stream>>>(
        (const fx4*)Offset, (const fx4*)meanp, RT, (fx4*)out);
}